// Round 12
// baseline (82.648 us; speedup 1.0000x reference)
//
#include <hip/hip_runtime.h>

// CAMixer agent-attention, fused per-window (8x8).  v12 = v11 + LDS repack + fused precompute:
//  - lifetime-aliased regions: RA{xp -> Lraw -> xv}, RB{gkq -> attn -> av};
//    qat/av K=32 zero rows synthesized in-register in P7 (not stored).
//    LDS 31,296 -> 25,024 B -> 6 blocks/CU (was 5). No new barriers.
//  - precompute fused to ONE kernel (frag Gram-dots computed directly from Wq/Wk,
//    same fmaf chain order -> bit-identical). 4 launches -> 2.
//  - s_setprio(1) around pure-reg MFMA clusters (T5).
//
// Algebra (exact refactor, verified round 1):
//   agent   = conv(pool(x), Wq)
//   k-logit[p][l] = xw[l]·gk[p] + bkd[p],  gk = xp @ Mk + bk2,  Mk = Wq^T Wk
//   q-logit[l][p] = xw[l]·gq[p] + bqd[p],  gq = xp @ Mq + bq2,  Mq = Wq^T Wq
//   agent_v = (a_attn @ xw) @ Wv^T + bv
//
// MFMA conventions (verified v5-v11):
//   A-frag: lane = row + 16*kblk holds A[row][ks*32 + kblk*8 + j], j=0..7
//   B-frag: lane = col + 16*kblk holds B[ks*32 + kblk*8 + j][col]
//   C-frag: col = lane&15, row = (lane>>4)*4 + reg
//
// XWS layout (v7-proven): element (c,l) at byte c*128 + ((l*2) ^ ((c&7)<<4))

constexpr int C_   = 96;
constexpr int Wimg = 192;
constexpr int HWp  = 192 * 192;
constexpr int NWIN = 24;
constexpr int Pp   = 7;

typedef __attribute__((ext_vector_type(8))) __bf16 bf16x8;
typedef __attribute__((ext_vector_type(4))) __bf16 bf16x4;
typedef __attribute__((ext_vector_type(8))) short  short8;
typedef __attribute__((ext_vector_type(4))) float  f32x4;
union frag_u { short8 s; bf16x8 b; };

// ---- LDS byte offsets (total 25,024 B -> 6 blocks/CU) ----
constexpr int XWS   = 0;        // xw bf16 [96][64], 128B rows, XOR-swizzled (12,288)
constexpr int RA    = 12288;    // 4,224: xp hi/lo [8][100] -> Lraw[16][66]f32 -> xv hi/lo
constexpr int XPH   = RA;
constexpr int XPL   = RA + 1600;
constexpr int LRAW  = RA;
constexpr int RB    = 16512;    // 6,400: gkq hi/lo [16][100] -> attn(4x1KB) -> av hi/lo [96][16B]
constexpr int GKQH  = RB;
constexpr int GKQL  = RB + 3200;
constexpr int AVH   = RB;
constexpr int AVL   = RB + 1536;
constexpr int QATH  = 22912;    // qat hi [64][16B]
constexpr int QATL  = 23936;    // qat lo [64][16B]
constexpr int BIAS  = 24960;    // f32[16]
constexpr int SMEMB = 25024;

// ---- ws offsets ----
constexpr int WS_BK2_F  = 18624;                        // float idx (bk2 96, bq2 96, scal 2)
constexpr int WS_BQ2_F  = 18720;
constexpr int WS_SCAL_F = 18816;
constexpr int WS_FRAG_BYTE = 18944 * 4;                 // Mext frags: 84 slots x 1KB
constexpr int WS_WV_BYTE   = WS_FRAG_BYTE + 84 * 1024;  // Wv frags: 36 slots x 1KB

// ---------------- helpers ----------------

__device__ __forceinline__ void bar() {
    asm volatile("s_waitcnt lgkmcnt(0)" ::: "memory");
    __builtin_amdgcn_s_barrier();
}

__device__ __forceinline__ short8 xws_fragA(const unsigned char* S, int mt, int ks, int lane) {
    const int c  = mt * 16 + (lane & 15);
    const int l2 = ks * 64 + ((lane >> 4) << 4);
    return *reinterpret_cast<const short8*>(S + XWS + c * 128 + (l2 ^ ((c & 7) << 4)));
}

__device__ __forceinline__ void put_hilo(unsigned char* S, int hi_off, int lo_off, float v) {
    const __bf16 h = (__bf16)v;
    *reinterpret_cast<__bf16*>(S + hi_off) = h;
    *reinterpret_cast<__bf16*>(S + lo_off) = (__bf16)(v - (float)h);
}

// ---------------- fused precompute (one kernel, 61 blocks x 64) ----------------
// bid<42: Mext B-frag pair (hi,lo).  bid 42..59: Wv A-frag pair.  bid 60: bk2/bq2/scal.

__global__ void precompute_all(const float* __restrict__ Wq,
                               const float* __restrict__ Wk,
                               const float* __restrict__ Wv,
                               const float* __restrict__ bq,
                               const float* __restrict__ bk,
                               float* __restrict__ ws,
                               unsigned char* __restrict__ wsb)
{
    const int bid = blockIdx.x, lane = threadIdx.x;
    if (bid < 42) {
        const int mat = bid / 21, rem = bid % 21;
        const int nt = rem / 3, ks = rem % 3;
        const float* __restrict__ W2 = mat ? Wq : Wk;
        const float* __restrict__ bvec = mat ? bq : bk;
        const int col = nt * 16 + (lane & 15);
        short8 oh, ol;
        #pragma unroll
        for (int j = 0; j < 8; ++j) {
            const int k = ks * 32 + (lane >> 4) * 8 + j;
            float raw = 0.f;
            if (col < 96) {
                for (int a = 0; a < C_; ++a)
                    raw = fmaf(Wq[a * C_ + k], W2[a * C_ + col], raw);
            } else if (col == 96) {
                for (int a = 0; a < C_; ++a)
                    raw = fmaf(Wq[a * C_ + k], bvec[a], raw);
            }
            const __bf16 hi = (__bf16)raw;
            union { __bf16 h; short s; } cv;
            cv.h = hi; oh[j] = cv.s;
            cv.h = (__bf16)(raw - (float)hi); ol[j] = cv.s;
        }
        const int slot = ((mat * 7 + nt) * 3 + ks) * 2;
        *reinterpret_cast<short8*>(wsb + WS_FRAG_BYTE + slot * 1024 + lane * 16) = oh;
        *reinterpret_cast<short8*>(wsb + WS_FRAG_BYTE + (slot + 1) * 1024 + lane * 16) = ol;
    } else if (bid < 60) {
        const int wb = bid - 42;
        const int mt = wb / 3, ks = wb % 3;
        const int row = mt * 16 + (lane & 15);
        short8 oh, ol;
        #pragma unroll
        for (int j = 0; j < 8; ++j) {
            const int c = ks * 32 + (lane >> 4) * 8 + j;
            const float raw = Wv[row * C_ + c];
            const __bf16 hi = (__bf16)raw;
            union { __bf16 h; short s; } cv;
            cv.h = hi; oh[j] = cv.s;
            cv.h = (__bf16)(raw - (float)hi); ol[j] = cv.s;
        }
        const int slot = (mt * 3 + ks) * 2;
        *reinterpret_cast<short8*>(wsb + WS_WV_BYTE + slot * 1024 + lane * 16) = oh;
        *reinterpret_cast<short8*>(wsb + WS_WV_BYTE + (slot + 1) * 1024 + lane * 16) = ol;
    } else {
        #pragma unroll
        for (int it = 0; it < 2; ++it) {
            const int c = lane + it * 64;
            if (c < 96) {
                float a_bk2 = 0.f, a_bq2 = 0.f;
                for (int a = 0; a < C_; ++a) {
                    a_bk2 = fmaf(bq[a], Wk[a * C_ + c], a_bk2);
                    a_bq2 = fmaf(bq[a], Wq[a * C_ + c], a_bq2);
                }
                ws[WS_BK2_F + c] = a_bk2;
                ws[WS_BQ2_F + c] = a_bq2;
            }
        }
        if (lane == 0) {
            float sk = 0.f, sq = 0.f;
            for (int a = 0; a < C_; ++a) { sk += bq[a] * bk[a]; sq += bq[a] * bq[a]; }
            ws[WS_SCAL_F]     = sk;
            ws[WS_SCAL_F + 1] = sq;
        }
    }
}

#define LOADPAIR(dstH, dstL, tab, slot_h) do {                                               \
    (dstH).s = *reinterpret_cast<const short8*>((tab) + (slot_h) * 1024 + (lane << 4));      \
    (dstL).s = *reinterpret_cast<const short8*>((tab) + ((slot_h) + 1) * 1024 + (lane << 4));\
} while (0)

// ---------------- main fused kernel ----------------

__global__ __launch_bounds__(256, 5) void camixer_main(
    const float* __restrict__ x,
    const float* __restrict__ bv,
    const float* __restrict__ bk2,
    const float* __restrict__ bq2,
    const float* __restrict__ scal,
    const unsigned char* __restrict__ mfrag,
    const unsigned char* __restrict__ wvfrag,
    float* __restrict__ out)
{
    __shared__ __align__(16) unsigned char S[SMEMB];
    float* Lraw   = (float*)(S + LRAW);  // [16][66]
    float* bias16 = (float*)(S + BIAS);  // [16]

    const int t = threadIdx.x;
    const int lane = t & 63, w = t >> 6;
    const int wid = ((blockIdx.x & 7) * 576) + (blockIdx.x >> 3);  // bijective XCD swizzle
    const int b  = wid / (NWIN * NWIN);
    const int r  = wid % (NWIN * NWIN);
    const int h0 = (r / NWIN) * 8;
    const int w0 = (r % NWIN) * 8;
    const int base = b * C_ * HWp + h0 * Wimg + w0;
    const float scal0 = scal[0], scal1 = scal[1];
    const short8 zero8 = {0, 0, 0, 0, 0, 0, 0, 0};

    // ---- prefetch G0 tile tt=w: in flight under P0 + G_P ----
    frag_u B0h[3], B0l[3];
    LOADPAIR(B0h[0], B0l[0], mfrag, (w * 3 + 0) * 2);
    LOADPAIR(B0h[1], B0l[1], mfrag, (w * 3 + 1) * 2);
    LOADPAIR(B0h[2], B0l[2], mfrag, (w * 3 + 2) * 2);

    // ---- P0: x window -> bf16 XOR-swizzled row-major (single copy) ----
    {
        const float4* x4 = reinterpret_cast<const float4*>(x);
        #pragma unroll
        for (int rr = 0; rr < 2; ++rr) {
            const int idx = t + (rr << 8);          // 384 = 24 c4 x 8 dh x 2 dw4
            if (idx < 384) {
                const int dw4 = idx & 1;
                const int dh  = (idx >> 1) & 7;
                const int c4  = idx >> 4;
                const int c0 = c4 * 4, l0 = dh * 8 + dw4 * 4;
                #pragma unroll
                for (int j = 0; j < 4; ++j) {
                    const int c = c0 + j;
                    const float4 v = x4[(base + c * HWp + dh * Wimg + dw4 * 4) >> 2];
                    bf16x4 d = {(__bf16)v.x, (__bf16)v.y, (__bf16)v.z, (__bf16)v.w};
                    *reinterpret_cast<bf16x4*>(S + XWS + c * 128 + ((l0 * 2) ^ ((c & 7) << 4))) = d;
                }
            }
        }
    }
    bar();

    // ---- G_P (MFMA): xp = P^T(hi/lo) @ xw^T ; write xp hi/lo (8 rows) ----
    {
        frag_u PAh[2], PAl[2];
        {
            const int p = lane & 15;
            const __bf16 PH = (__bf16)0.1f;
            const __bf16 PL = (__bf16)(0.1f - (float)PH);
            const int sp = (p < 7) ? ((p << 6) / 7) : 1000;
            #pragma unroll
            for (int ks = 0; ks < 2; ++ks)
                #pragma unroll
                for (int j = 0; j < 8; ++j) {
                    const int l = ks * 32 + (lane >> 4) * 8 + j;
                    const bool in = (l >= sp) && (l < sp + 10);
                    PAh[ks].b[j] = in ? PH : (__bf16)0.f;
                    PAl[ks].b[j] = in ? PL : (__bf16)0.f;
                }
        }
        #pragma unroll
        for (int rnd = 0; rnd < 2; ++rnd) {
            const int nt = rnd ? (4 + w) : w;
            if (rnd == 0 || w < 2) {
                f32x4 acc = {0.f, 0.f, 0.f, 0.f};
                __builtin_amdgcn_s_setprio(1);
                #pragma unroll
                for (int ks = 0; ks < 2; ++ks) {
                    frag_u B;
                    B.s = xws_fragA(S, nt, ks, lane);
                    acc = __builtin_amdgcn_mfma_f32_16x16x32_bf16(PAh[ks].b, B.b, acc, 0, 0, 0);
                    acc = __builtin_amdgcn_mfma_f32_16x16x32_bf16(PAl[ks].b, B.b, acc, 0, 0, 0);
                }
                __builtin_amdgcn_s_setprio(0);
                const int cc = nt * 16 + (lane & 15);
                #pragma unroll
                for (int rr = 0; rr < 4; ++rr) {
                    const int p = (lane >> 4) * 4 + rr;
                    if (p < 8)
                        put_hilo(S, XPH + p * 200 + cc * 2, XPL + p * 200 + cc * 2, acc[rr]);
                }
            }
        }
    }
    bar();

    // ---- G0 (MFMA, pipelined): gkq = xp(hi/lo) @ Mext(hi/lo); nt6 = bias dots ----
    {
        frag_u Ah[3], Al[3];
        #pragma unroll
        for (int ks = 0; ks < 3; ++ks) {
            const int off = ((lane & 15) & 7) * 200 + (ks * 32 + (lane >> 4) * 8) * 2;
            Ah[ks].s = *reinterpret_cast<const short8*>(S + XPH + off);
            Al[ks].s = *reinterpret_cast<const short8*>(S + XPL + off);
        }

        #define G0TILE(TT, BH, BL) do {                                               \
            const int tt_ = (TT);                                                     \
            const int mat_ = (tt_ >= 7) ? 1 : 0;                                      \
            const int nt_  = tt_ - 7 * mat_;                                          \
            f32x4 acc = {0.f, 0.f, 0.f, 0.f};                                         \
            __builtin_amdgcn_s_setprio(1);                                            \
            acc = __builtin_amdgcn_mfma_f32_16x16x32_bf16(Ah[0].b, BH[0].b, acc, 0,0,0); \
            acc = __builtin_amdgcn_mfma_f32_16x16x32_bf16(Ah[0].b, BL[0].b, acc, 0,0,0); \
            acc = __builtin_amdgcn_mfma_f32_16x16x32_bf16(Al[0].b, BH[0].b, acc, 0,0,0); \
            acc = __builtin_amdgcn_mfma_f32_16x16x32_bf16(Ah[1].b, BH[1].b, acc, 0,0,0); \
            acc = __builtin_amdgcn_mfma_f32_16x16x32_bf16(Ah[1].b, BL[1].b, acc, 0,0,0); \
            acc = __builtin_amdgcn_mfma_f32_16x16x32_bf16(Al[1].b, BH[1].b, acc, 0,0,0); \
            acc = __builtin_amdgcn_mfma_f32_16x16x32_bf16(Ah[2].b, BH[2].b, acc, 0,0,0); \
            acc = __builtin_amdgcn_mfma_f32_16x16x32_bf16(Ah[2].b, BL[2].b, acc, 0,0,0); \
            acc = __builtin_amdgcn_mfma_f32_16x16x32_bf16(Al[2].b, BH[2].b, acc, 0,0,0); \
            __builtin_amdgcn_s_setprio(0);                                            \
            const int row0_ = (lane >> 4) * 4;                                        \
            if (nt_ < 6) {                                                            \
                const int cc_ = nt_ * 16 + (lane & 15);                               \
                const float b2v_ = (mat_ ? bq2 : bk2)[cc_];                           \
                _Pragma("unroll")                                                     \
                for (int rr = 0; rr < 4; ++rr) {                                      \
                    const int rw_ = row0_ + rr;                                       \
                    if (rw_ < 8) {                                                    \
                        const int pr_ = rw_ + 8 * mat_;                               \
                        put_hilo(S, GKQH + pr_ * 200 + cc_ * 2,                       \
                                 GKQL + pr_ * 200 + cc_ * 2, acc[rr] + b2v_);         \
                    }                                                                 \
                }                                                                     \
            } else if ((lane & 15) == 0) {                                            \
                _Pragma("unroll")                                                     \
                for (int rr = 0; rr < 4; ++rr) {                                      \
                    const int rw_ = row0_ + rr;                                       \
                    if (rw_ < 8) bias16[rw_ + 8 * mat_] = acc[rr];                    \
                }                                                                     \
            }                                                                         \
        } while (0)

        frag_u B1h[3], B1l[3], B2h[3], B2l[3], B3h[3], B3l[3];
        LOADPAIR(B1h[0], B1l[0], mfrag, ((w + 4) * 3 + 0) * 2);
        LOADPAIR(B1h[1], B1l[1], mfrag, ((w + 4) * 3 + 1) * 2);
        LOADPAIR(B1h[2], B1l[2], mfrag, ((w + 4) * 3 + 2) * 2);
        G0TILE(w, B0h, B0l);
        LOADPAIR(B2h[0], B2l[0], mfrag, ((w + 8) * 3 + 0) * 2);
        LOADPAIR(B2h[1], B2l[1], mfrag, ((w + 8) * 3 + 1) * 2);
        LOADPAIR(B2h[2], B2l[2], mfrag, ((w + 8) * 3 + 2) * 2);
        G0TILE(w + 4, B1h, B1l);
        if (w < 2) {
            LOADPAIR(B3h[0], B3l[0], mfrag, ((w + 12) * 3 + 0) * 2);
            LOADPAIR(B3h[1], B3l[1], mfrag, ((w + 12) * 3 + 1) * 2);
            LOADPAIR(B3h[2], B3l[2], mfrag, ((w + 12) * 3 + 2) * 2);
        }
        G0TILE(w + 8, B2h, B2l);
        if (w < 2) G0TILE(w + 12, B3h, B3l);
        #undef G0TILE
    }
    bar();

    // ---- G1 (MFMA): L^T = gkq(hi/lo) @ xw + bias ; B via u16 gather from XWS ----
    {
        frag_u B[3];
        {
            const int l2 = (w * 16 + (lane & 15)) * 2;
            const int kb = (lane >> 4) << 10;
            #pragma unroll
            for (int j = 0; j < 8; ++j) {
                const int aj = kb + j * 128 + (l2 ^ (j << 4));
                B[0].b[j] = *reinterpret_cast<const __bf16*>(S + XWS + aj);
                B[1].b[j] = *reinterpret_cast<const __bf16*>(S + XWS + 4096 + aj);
                B[2].b[j] = *reinterpret_cast<const __bf16*>(S + XWS + 8192 + aj);
            }
        }
        frag_u Ah[3], Al[3];
        #pragma unroll
        for (int ks = 0; ks < 3; ++ks) {
            const int off = (lane & 15) * 200 + (ks * 32 + (lane >> 4) * 8) * 2;
            Ah[ks].s = *reinterpret_cast<const short8*>(S + GKQH + off);
            Al[ks].s = *reinterpret_cast<const short8*>(S + GKQL + off);
        }
        f32x4 acc = {0.f, 0.f, 0.f, 0.f};
        __builtin_amdgcn_s_setprio(1);
        #pragma unroll
        for (int ks = 0; ks < 3; ++ks) {
            acc = __builtin_amdgcn_mfma_f32_16x16x32_bf16(Ah[ks].b, B[ks].b, acc, 0, 0, 0);
            acc = __builtin_amdgcn_mfma_f32_16x16x32_bf16(Al[ks].b, B[ks].b, acc, 0, 0, 0);
        }
        __builtin_amdgcn_s_setprio(0);
        const int colL = w * 16 + (lane & 15);
        #pragma unroll
        for (int rr = 0; rr < 4; ++rr) {
            const int pr = (lane >> 4) * 4 + rr;
            Lraw[pr * 66 + colL] = acc[rr] + bias16[pr] + (pr < 8 ? scal0 : scal1);
        }
    }
    bar();

    // ---- SM: k-softmax rows over waves; q-softmax + qat hi/lo on wave 3 ----
    if (w < 3) {
        #pragma unroll
        for (int rr = 0; rr < 2; ++rr) {
            const int pp = w + 3 * rr;               // rows 0..5
            const float v = Lraw[pp * 66 + lane];
            float mx = v;
            #pragma unroll
            for (int off = 32; off; off >>= 1) mx = fmaxf(mx, __shfl_xor(mx, off));
            const float e = __expf(v - mx);
            float s = e;
            #pragma unroll
            for (int off = 32; off; off >>= 1) s += __shfl_xor(s, off);
            const float a = e / s;
            const __bf16 hb = (__bf16)a;
            const __bf16 lb = (__bf16)(a - (float)hb);
            const int ks = lane >> 5;
            const int off_b = ((pp + 16 * ((lane >> 3) & 3)) << 4) + ((lane & 7) << 1);
            *reinterpret_cast<__bf16*>(S + RB + (ks << 10) + off_b) = hb;
            *reinterpret_cast<__bf16*>(S + RB + ((2 + ks) << 10) + off_b) = lb;
        }
    } else {
        {
            const int pp = 6;
            const float v = Lraw[pp * 66 + lane];
            float mx = v;
            #pragma unroll
            for (int off = 32; off; off >>= 1) mx = fmaxf(mx, __shfl_xor(mx, off));
            const float e = __expf(v - mx);
            float s = e;
            #pragma unroll
            for (int off = 32; off; off >>= 1) s += __shfl_xor(s, off);
            const float a = e / s;
            const __bf16 hb = (__bf16)a;
            const __bf16 lb = (__bf16)(a - (float)hb);
            const int ks = lane >> 5;
            const int off_b = ((pp + 16 * ((lane >> 3) & 3)) << 4) + ((lane & 7) << 1);
            *reinterpret_cast<__bf16*>(S + RB + (ks << 10) + off_b) = hb;
            *reinterpret_cast<__bf16*>(S + RB + ((2 + ks) << 10) + off_b) = lb;
        }
        float vv[Pp];
        float mx = -1e30f;
        #pragma unroll
        for (int p = 0; p < Pp; ++p) { vv[p] = Lraw[(8 + p) * 66 + lane]; mx = fmaxf(mx, vv[p]); }
        float s = 0.f;
        #pragma unroll
        for (int p = 0; p < Pp; ++p) { vv[p] = __expf(vv[p] - mx); s += vv[p]; }
        const float inv = 1.f / s;
        frag_u qh, ql;
        #pragma unroll
        for (int p = 0; p < 8; ++p) {
            const float a = (p < Pp) ? vv[p] * inv : 0.f;
            const __bf16 hb = (__bf16)a;
            qh.b[p] = hb;
            ql.b[p] = (__bf16)(a - (float)hb);
        }
        *reinterpret_cast<short8*>(S + QATH + lane * 16) = qh.s;
        *reinterpret_cast<short8*>(S + QATL + lane * 16) = ql.s;
    }
    bar();

    // ---- G2 (MFMA) + wvfrag prefetch: xv^T = xw @ attn(hi/lo); write xv hi/lo ----
    frag_u V0h[3], V0l[3], V1h[3], V1l[3];
    {
        LOADPAIR(V0h[0], V0l[0], wvfrag, (w * 3 + 0) * 2);
        LOADPAIR(V0h[1], V0l[1], wvfrag, (w * 3 + 1) * 2);
        LOADPAIR(V0h[2], V0l[2], wvfrag, (w * 3 + 2) * 2);
        if (w < 2) {
            LOADPAIR(V1h[0], V1l[0], wvfrag, ((4 + w) * 3 + 0) * 2);
            LOADPAIR(V1h[1], V1l[1], wvfrag, ((4 + w) * 3 + 1) * 2);
            LOADPAIR(V1h[2], V1l[2], wvfrag, ((4 + w) * 3 + 2) * 2);
        }

        frag_u Bh[2], Bl[2];
        #pragma unroll
        for (int ks = 0; ks < 2; ++ks) {
            Bh[ks].s = *reinterpret_cast<const short8*>(S + RB + (ks << 10) + (lane << 4));
            Bl[ks].s = *reinterpret_cast<const short8*>(S + RB + ((2 + ks) << 10) + (lane << 4));
        }
        const int mt0 = (w < 2) ? w * 2 : (w + 2);
        const int nmt = (w < 2) ? 2 : 1;
        for (int m = 0; m < nmt; ++m) {
            const int mt = mt0 + m;
            f32x4 acc = {0.f, 0.f, 0.f, 0.f};
            __builtin_amdgcn_s_setprio(1);
            #pragma unroll
            for (int ks = 0; ks < 2; ++ks) {
                frag_u A;
                A.s = xws_fragA(S, mt, ks, lane);
                acc = __builtin_amdgcn_mfma_f32_16x16x32_bf16(A.b, Bh[ks].b, acc, 0, 0, 0);
                acc = __builtin_amdgcn_mfma_f32_16x16x32_bf16(A.b, Bl[ks].b, acc, 0, 0, 0);
            }
            __builtin_amdgcn_s_setprio(0);
            const int p = lane & 15;
            if (p < 8) {                              // rows >=8 never read; avoid lo-image clobber
                #pragma unroll
                for (int rr = 0; rr < 4; ++rr) {
                    const int c = mt * 16 + (lane >> 4) * 4 + rr;
                    put_hilo(S, XPH + p * 200 + c * 2, XPL + p * 200 + c * 2, acc[rr]);
                }
            }
        }
    }
    bar();

    // ---- G3 (MFMA): av^T = Wv(hi/lo) @ xv(hi/lo) + bv; write av hi/lo [96][16B] ----
    {
        const bool pok = (lane & 15) < Pp;           // garbage guard (xv row 7 junk cols)
        frag_u Bh[3], Bl[3];
        #pragma unroll
        for (int ks = 0; ks < 3; ++ks) {
            const int off = ((lane & 15) & 7) * 200 + (ks * 32 + (lane >> 4) * 8) * 2;
            Bh[ks].s = pok ? *reinterpret_cast<const short8*>(S + XPH + off) : zero8;
            Bl[ks].s = pok ? *reinterpret_cast<const short8*>(S + XPL + off) : zero8;
        }
        #define G3TILE(MT, VH, VL) do {                                               \
            f32x4 acc = {0.f, 0.f, 0.f, 0.f};                                         \
            __builtin_amdgcn_s_setprio(1);                                            \
            acc = __builtin_amdgcn_mfma_f32_16x16x32_bf16(VH[0].b, Bh[0].b, acc, 0,0,0); \
            acc = __builtin_amdgcn_mfma_f32_16x16x32_bf16(VH[0].b, Bl[0].b, acc, 0,0,0); \
            acc = __builtin_amdgcn_mfma_f32_16x16x32_bf16(VL[0].b, Bh[0].b, acc, 0,0,0); \
            acc = __builtin_amdgcn_mfma_f32_16x16x32_bf16(VH[1].b, Bh[1].b, acc, 0,0,0); \
            acc = __builtin_amdgcn_mfma_f32_16x16x32_bf16(VH[1].b, Bl[1].b, acc, 0,0,0); \
            acc = __builtin_amdgcn_mfma_f32_16x16x32_bf16(VL[1].b, Bh[1].b, acc, 0,0,0); \
            acc = __builtin_amdgcn_mfma_f32_16x16x32_bf16(VH[2].b, Bh[2].b, acc, 0,0,0); \
            acc = __builtin_amdgcn_mfma_f32_16x16x32_bf16(VH[2].b, Bl[2].b, acc, 0,0,0); \
            acc = __builtin_amdgcn_mfma_f32_16x16x32_bf16(VL[2].b, Bh[2].b, acc, 0,0,0); \
            __builtin_amdgcn_s_setprio(0);                                            \
            if ((lane & 15) < 8) {                                                    \
                _Pragma("unroll")                                                     \
                for (int rr = 0; rr < 4; ++rr) {                                      \
                    const int o_ = (MT) * 16 + (lane >> 4) * 4 + rr;                  \
                    const float v_ = acc[rr] + bv[o_];                                \
                    put_hilo(S, AVH + o_ * 16 + (lane & 15) * 2,                      \
                             AVL + o_ * 16 + (lane & 15) * 2, v_);                    \
                }                                                                     \
            }                                                                         \
        } while (0)
        G3TILE(w, V0h, V0l);
        if (w < 2) G3TILE(4 + w, V1h, V1l);
        #undef G3TILE
    }
    bar();

    // ---- P7 (MFMA): out^T[96o][64l] = av_ext @ qat^T (K=32; k>=8 zero in-register) ----
    {
        const int kblk = lane >> 4, nlow = lane & 15;
        const int l = w * 16 + nlow;
        frag_u Bh, Bl;
        if (kblk == 0) {
            Bh.s = *reinterpret_cast<const short8*>(S + QATH + l * 16);
            Bl.s = *reinterpret_cast<const short8*>(S + QATL + l * 16);
        } else { Bh.s = zero8; Bl.s = zero8; }
        const int obase = b * C_ * HWp + (h0 + (l >> 3)) * Wimg + w0 + (l & 7);
        #pragma unroll
        for (int mt = 0; mt < 6; ++mt) {
            frag_u Ah, Al;
            if (kblk == 0) {
                Ah.s = *reinterpret_cast<const short8*>(S + AVH + (mt * 16 + nlow) * 16);
                Al.s = *reinterpret_cast<const short8*>(S + AVL + (mt * 16 + nlow) * 16);
            } else { Ah.s = zero8; Al.s = zero8; }
            f32x4 acc = {0.f, 0.f, 0.f, 0.f};
            __builtin_amdgcn_s_setprio(1);
            acc = __builtin_amdgcn_mfma_f32_16x16x32_bf16(Ah.b, Bh.b, acc, 0, 0, 0);
            acc = __builtin_amdgcn_mfma_f32_16x16x32_bf16(Ah.b, Bl.b, acc, 0, 0, 0);
            acc = __builtin_amdgcn_mfma_f32_16x16x32_bf16(Al.b, Bh.b, acc, 0, 0, 0);
            __builtin_amdgcn_s_setprio(0);
            #pragma unroll
            for (int rr = 0; rr < 4; ++rr) {
                const int o = mt * 16 + kblk * 4 + rr;
                out[obase + o * HWp] = acc[rr];
            }
        }
    }
}

// ---------------- launch ----------------

extern "C" void kernel_launch(void* const* d_in, const int* in_sizes, int n_in,
                              void* d_out, int out_size, void* d_ws, size_t ws_size,
                              hipStream_t stream)
{
    const float* x  = (const float*)d_in[0];
    const float* Wv = (const float*)d_in[1];
    const float* bv = (const float*)d_in[2];
    const float* Wq = (const float*)d_in[3];
    const float* bq = (const float*)d_in[4];
    const float* Wk = (const float*)d_in[5];
    const float* bk = (const float*)d_in[6];
    float* out = (float*)d_out;

    float* ws = (float*)d_ws;
    unsigned char* wsb = (unsigned char*)d_ws;

    hipLaunchKernelGGL(precompute_all, dim3(61), dim3(64), 0, stream,
                       Wq, Wk, Wv, bq, bk, ws, wsb);
    hipLaunchKernelGGL(camixer_main, dim3(8 * NWIN * NWIN), dim3(256), 0, stream,
                       x, bv, ws + WS_BK2_F, ws + WS_BQ2_F, ws + WS_SCAL_F,
                       wsb + WS_FRAG_BYTE, wsb + WS_WV_BYTE, out);
}

// Round 13
// 75.708 us; speedup vs baseline: 1.0917x; 1.0917x over previous
//
#include <hip/hip_runtime.h>

// CAMixer agent-attention, fused per-window (8x8).  v13 = v12 main (LDS 25KB repack)
// with the two counter-indicted regressions reverted:
//  - precompute back to v11's fast 3-kernel pipeline (row-coalesced Gram kernel);
//    v12's fused precompute cost ~+7us serial (uncoalesced 96-deep dots, 61 blocks).
//  - s_setprio removed (m190: null-to-negative on barrier-lockstep GEMM phases).
//
// Algebra (exact refactor, verified round 1):
//   agent   = conv(pool(x), Wq)
//   k-logit[p][l] = xw[l]·gk[p] + bkd[p],  gk = xp @ Mk + bk2,  Mk = Wq^T Wk
//   q-logit[l][p] = xw[l]·gq[p] + bqd[p],  gq = xp @ Mq + bq2,  Mq = Wq^T Wq
//   agent_v = (a_attn @ xw) @ Wv^T + bv
//
// MFMA conventions (verified v5-v12):
//   A-frag: lane = row + 16*kblk holds A[row][ks*32 + kblk*8 + j], j=0..7
//   B-frag: lane = col + 16*kblk holds B[ks*32 + kblk*8 + j][col]
//   C-frag: col = lane&15, row = (lane>>4)*4 + reg
//
// XWS layout (v7-proven): element (c,l) at byte c*128 + ((l*2) ^ ((c&7)<<4))

constexpr int C_   = 96;
constexpr int Wimg = 192;
constexpr int HWp  = 192 * 192;
constexpr int NWIN = 24;
constexpr int Pp   = 7;

typedef __attribute__((ext_vector_type(8))) __bf16 bf16x8;
typedef __attribute__((ext_vector_type(4))) __bf16 bf16x4;
typedef __attribute__((ext_vector_type(8))) short  short8;
typedef __attribute__((ext_vector_type(4))) float  f32x4;
union frag_u { short8 s; bf16x8 b; };

// ---- LDS byte offsets (total 25,024 B) ----
constexpr int XWS   = 0;        // xw bf16 [96][64], 128B rows, XOR-swizzled (12,288)
constexpr int RA    = 12288;    // 4,224: xp hi/lo [8][100] -> Lraw[16][66]f32 -> xv hi/lo
constexpr int XPH   = RA;
constexpr int XPL   = RA + 1600;
constexpr int LRAW  = RA;
constexpr int RB    = 16512;    // 6,400: gkq hi/lo [16][100] -> attn(4x1KB) -> av hi/lo [96][16B]
constexpr int GKQH  = RB;
constexpr int GKQL  = RB + 3200;
constexpr int AVH   = RB;
constexpr int AVL   = RB + 1536;
constexpr int QATH  = 22912;    // qat hi [64][16B]
constexpr int QATL  = 23936;    // qat lo [64][16B]
constexpr int BIAS  = 24960;    // f32[16]
constexpr int SMEMB = 25024;

// ---- ws offsets ----
// float idx: Mk 0, Mq 9216, uk 18432, uq 18528, bk2 18624, bq2 18720, scal 18816
constexpr int WS_FRAG_BYTE = 18944 * 4;                 // Mext frags: 84 slots x 1KB
constexpr int WS_WV_BYTE   = WS_FRAG_BYTE + 84 * 1024;  // Wv frags: 36 slots x 1KB

// ---------------- helpers ----------------

__device__ __forceinline__ void bar() {
    asm volatile("s_waitcnt lgkmcnt(0)" ::: "memory");
    __builtin_amdgcn_s_barrier();
}

__device__ __forceinline__ short8 xws_fragA(const unsigned char* S, int mt, int ks, int lane) {
    const int c  = mt * 16 + (lane & 15);
    const int l2 = ks * 64 + ((lane >> 4) << 4);
    return *reinterpret_cast<const short8*>(S + XWS + c * 128 + (l2 ^ ((c & 7) << 4)));
}

__device__ __forceinline__ void put_hilo(unsigned char* S, int hi_off, int lo_off, float v) {
    const __bf16 h = (__bf16)v;
    *reinterpret_cast<__bf16*>(S + hi_off) = h;
    *reinterpret_cast<__bf16*>(S + lo_off) = (__bf16)(v - (float)h);
}

// ---------------- precompute (weights only, trivial cost; v11-proven) ----------------

__global__ void precompute_mats(const float* __restrict__ Wq,
                                const float* __restrict__ Wk,
                                float* __restrict__ Mk,
                                float* __restrict__ Mq)
{
    const int c  = blockIdx.x;
    const int cp = threadIdx.x;
    float ak = 0.f, aq = 0.f;
    for (int a = 0; a < C_; ++a) {
        const float wq = Wq[a * C_ + c];
        ak = fmaf(wq, Wk[a * C_ + cp], ak);
        aq = fmaf(wq, Wq[a * C_ + cp], aq);
    }
    Mk[c * C_ + cp] = ak;
    Mq[c * C_ + cp] = aq;
}

__global__ void precompute_vecs(const float* __restrict__ Wq,
                                const float* __restrict__ Wk,
                                const float* __restrict__ bq,
                                const float* __restrict__ bk,
                                float* __restrict__ uk,  float* __restrict__ uq,
                                float* __restrict__ bk2, float* __restrict__ bq2,
                                float* __restrict__ scal)
{
    const int c = threadIdx.x;
    float a_uk = 0.f, a_uq = 0.f, a_bk2 = 0.f, a_bq2 = 0.f;
    for (int a = 0; a < C_; ++a) {
        const float wqc = Wq[a * C_ + c];
        a_uk  = fmaf(wqc, bk[a], a_uk);
        a_uq  = fmaf(wqc, bq[a], a_uq);
        a_bk2 = fmaf(bq[a], Wk[a * C_ + c], a_bk2);
        a_bq2 = fmaf(bq[a], Wq[a * C_ + c], a_bq2);
    }
    uk[c] = a_uk; uq[c] = a_uq; bk2[c] = a_bk2; bq2[c] = a_bq2;
    if (c == 0) {
        float sk = 0.f, sq = 0.f;
        for (int a = 0; a < C_; ++a) { sk += bq[a] * bk[a]; sq += bq[a] * bq[a]; }
        scal[0] = sk; scal[1] = sq;
    }
}

// frag tables: bid<84: Mext B-frags slot=((mat*7+nt)*3+ks)*2+hl; else Wv A-frags.
__global__ void precompute_frags(const float* __restrict__ ws,
                                 const float* __restrict__ Wv,
                                 unsigned char* __restrict__ wsb)
{
    const int bid = blockIdx.x, lane = threadIdx.x;
    short8 o;
    if (bid < 84) {
        const int hl = bid & 1, ks = (bid >> 1) % 3, nt = (bid / 6) % 7, mat = bid / 42;
        const float* M = ws + (mat ? 9216 : 0);
        const float* u = ws + (mat ? 18528 : 18432);
        const int col = nt * 16 + (lane & 15);
        #pragma unroll
        for (int j = 0; j < 8; ++j) {
            const int k = ks * 32 + (lane >> 4) * 8 + j;
            const float raw = (col < 96) ? M[k * 96 + col] : ((col == 96) ? u[k] : 0.f);
            const __bf16 hi = (__bf16)raw;
            union { __bf16 h; short s; } cv;
            cv.h = hl ? (__bf16)(raw - (float)hi) : hi;
            o[j] = cv.s;
        }
        *reinterpret_cast<short8*>(wsb + WS_FRAG_BYTE + bid * 1024 + lane * 16) = o;
    } else {
        const int wb = bid - 84;
        const int hl = wb & 1, ks = (wb >> 1) % 3, mt = wb / 6;
        const int row = mt * 16 + (lane & 15);
        #pragma unroll
        for (int j = 0; j < 8; ++j) {
            const int c = ks * 32 + (lane >> 4) * 8 + j;
            const float raw = Wv[row * 96 + c];
            const __bf16 hi = (__bf16)raw;
            union { __bf16 h; short s; } cv;
            cv.h = hl ? (__bf16)(raw - (float)hi) : hi;
            o[j] = cv.s;
        }
        *reinterpret_cast<short8*>(wsb + WS_WV_BYTE + wb * 1024 + lane * 16) = o;
    }
}

#define LOADPAIR(dstH, dstL, tab, slot_h) do {                                               \
    (dstH).s = *reinterpret_cast<const short8*>((tab) + (slot_h) * 1024 + (lane << 4));      \
    (dstL).s = *reinterpret_cast<const short8*>((tab) + ((slot_h) + 1) * 1024 + (lane << 4));\
} while (0)

// ---------------- main fused kernel ----------------

__global__ __launch_bounds__(256, 5) void camixer_main(
    const float* __restrict__ x,
    const float* __restrict__ bv,
    const float* __restrict__ bk2,
    const float* __restrict__ bq2,
    const float* __restrict__ scal,
    const unsigned char* __restrict__ mfrag,
    const unsigned char* __restrict__ wvfrag,
    float* __restrict__ out)
{
    __shared__ __align__(16) unsigned char S[SMEMB];
    float* Lraw   = (float*)(S + LRAW);  // [16][66]
    float* bias16 = (float*)(S + BIAS);  // [16]

    const int t = threadIdx.x;
    const int lane = t & 63, w = t >> 6;
    const int wid = ((blockIdx.x & 7) * 576) + (blockIdx.x >> 3);  // bijective XCD swizzle
    const int b  = wid / (NWIN * NWIN);
    const int r  = wid % (NWIN * NWIN);
    const int h0 = (r / NWIN) * 8;
    const int w0 = (r % NWIN) * 8;
    const int base = b * C_ * HWp + h0 * Wimg + w0;
    const float scal0 = scal[0], scal1 = scal[1];
    const short8 zero8 = {0, 0, 0, 0, 0, 0, 0, 0};

    // ---- prefetch G0 tile tt=w: in flight under P0 + G_P ----
    frag_u B0h[3], B0l[3];
    LOADPAIR(B0h[0], B0l[0], mfrag, (w * 3 + 0) * 2);
    LOADPAIR(B0h[1], B0l[1], mfrag, (w * 3 + 1) * 2);
    LOADPAIR(B0h[2], B0l[2], mfrag, (w * 3 + 2) * 2);

    // ---- P0: x window -> bf16 XOR-swizzled row-major (single copy) ----
    {
        const float4* x4 = reinterpret_cast<const float4*>(x);
        #pragma unroll
        for (int rr = 0; rr < 2; ++rr) {
            const int idx = t + (rr << 8);          // 384 = 24 c4 x 8 dh x 2 dw4
            if (idx < 384) {
                const int dw4 = idx & 1;
                const int dh  = (idx >> 1) & 7;
                const int c4  = idx >> 4;
                const int c0 = c4 * 4, l0 = dh * 8 + dw4 * 4;
                #pragma unroll
                for (int j = 0; j < 4; ++j) {
                    const int c = c0 + j;
                    const float4 v = x4[(base + c * HWp + dh * Wimg + dw4 * 4) >> 2];
                    bf16x4 d = {(__bf16)v.x, (__bf16)v.y, (__bf16)v.z, (__bf16)v.w};
                    *reinterpret_cast<bf16x4*>(S + XWS + c * 128 + ((l0 * 2) ^ ((c & 7) << 4))) = d;
                }
            }
        }
    }
    bar();

    // ---- G_P (MFMA): xp = P^T(hi/lo) @ xw^T ; write xp hi/lo (8 rows) ----
    {
        frag_u PAh[2], PAl[2];
        {
            const int p = lane & 15;
            const __bf16 PH = (__bf16)0.1f;
            const __bf16 PL = (__bf16)(0.1f - (float)PH);
            const int sp = (p < 7) ? ((p << 6) / 7) : 1000;
            #pragma unroll
            for (int ks = 0; ks < 2; ++ks)
                #pragma unroll
                for (int j = 0; j < 8; ++j) {
                    const int l = ks * 32 + (lane >> 4) * 8 + j;
                    const bool in = (l >= sp) && (l < sp + 10);
                    PAh[ks].b[j] = in ? PH : (__bf16)0.f;
                    PAl[ks].b[j] = in ? PL : (__bf16)0.f;
                }
        }
        #pragma unroll
        for (int rnd = 0; rnd < 2; ++rnd) {
            const int nt = rnd ? (4 + w) : w;
            if (rnd == 0 || w < 2) {
                f32x4 acc = {0.f, 0.f, 0.f, 0.f};
                #pragma unroll
                for (int ks = 0; ks < 2; ++ks) {
                    frag_u B;
                    B.s = xws_fragA(S, nt, ks, lane);
                    acc = __builtin_amdgcn_mfma_f32_16x16x32_bf16(PAh[ks].b, B.b, acc, 0, 0, 0);
                    acc = __builtin_amdgcn_mfma_f32_16x16x32_bf16(PAl[ks].b, B.b, acc, 0, 0, 0);
                }
                const int cc = nt * 16 + (lane & 15);
                #pragma unroll
                for (int rr = 0; rr < 4; ++rr) {
                    const int p = (lane >> 4) * 4 + rr;
                    if (p < 8)
                        put_hilo(S, XPH + p * 200 + cc * 2, XPL + p * 200 + cc * 2, acc[rr]);
                }
            }
        }
    }
    bar();

    // ---- G0 (MFMA, pipelined): gkq = xp(hi/lo) @ Mext(hi/lo); nt6 = bias dots ----
    {
        frag_u Ah[3], Al[3];
        #pragma unroll
        for (int ks = 0; ks < 3; ++ks) {
            const int off = ((lane & 15) & 7) * 200 + (ks * 32 + (lane >> 4) * 8) * 2;
            Ah[ks].s = *reinterpret_cast<const short8*>(S + XPH + off);
            Al[ks].s = *reinterpret_cast<const short8*>(S + XPL + off);
        }

        #define G0TILE(TT, BH, BL) do {                                               \
            const int tt_ = (TT);                                                     \
            const int mat_ = (tt_ >= 7) ? 1 : 0;                                      \
            const int nt_  = tt_ - 7 * mat_;                                          \
            f32x4 acc = {0.f, 0.f, 0.f, 0.f};                                         \
            acc = __builtin_amdgcn_mfma_f32_16x16x32_bf16(Ah[0].b, BH[0].b, acc, 0,0,0); \
            acc = __builtin_amdgcn_mfma_f32_16x16x32_bf16(Ah[0].b, BL[0].b, acc, 0,0,0); \
            acc = __builtin_amdgcn_mfma_f32_16x16x32_bf16(Al[0].b, BH[0].b, acc, 0,0,0); \
            acc = __builtin_amdgcn_mfma_f32_16x16x32_bf16(Ah[1].b, BH[1].b, acc, 0,0,0); \
            acc = __builtin_amdgcn_mfma_f32_16x16x32_bf16(Ah[1].b, BL[1].b, acc, 0,0,0); \
            acc = __builtin_amdgcn_mfma_f32_16x16x32_bf16(Al[1].b, BH[1].b, acc, 0,0,0); \
            acc = __builtin_amdgcn_mfma_f32_16x16x32_bf16(Ah[2].b, BH[2].b, acc, 0,0,0); \
            acc = __builtin_amdgcn_mfma_f32_16x16x32_bf16(Ah[2].b, BL[2].b, acc, 0,0,0); \
            acc = __builtin_amdgcn_mfma_f32_16x16x32_bf16(Al[2].b, BH[2].b, acc, 0,0,0); \
            const int row0_ = (lane >> 4) * 4;                                        \
            if (nt_ < 6) {                                                            \
                const int cc_ = nt_ * 16 + (lane & 15);                               \
                const float b2v_ = (mat_ ? bq2 : bk2)[cc_];                           \
                _Pragma("unroll")                                                     \
                for (int rr = 0; rr < 4; ++rr) {                                      \
                    const int rw_ = row0_ + rr;                                       \
                    if (rw_ < 8) {                                                    \
                        const int pr_ = rw_ + 8 * mat_;                               \
                        put_hilo(S, GKQH + pr_ * 200 + cc_ * 2,                       \
                                 GKQL + pr_ * 200 + cc_ * 2, acc[rr] + b2v_);         \
                    }                                                                 \
                }                                                                     \
            } else if ((lane & 15) == 0) {                                            \
                _Pragma("unroll")                                                     \
                for (int rr = 0; rr < 4; ++rr) {                                      \
                    const int rw_ = row0_ + rr;                                       \
                    if (rw_ < 8) bias16[rw_ + 8 * mat_] = acc[rr];                    \
                }                                                                     \
            }                                                                         \
        } while (0)

        frag_u B1h[3], B1l[3], B2h[3], B2l[3], B3h[3], B3l[3];
        LOADPAIR(B1h[0], B1l[0], mfrag, ((w + 4) * 3 + 0) * 2);
        LOADPAIR(B1h[1], B1l[1], mfrag, ((w + 4) * 3 + 1) * 2);
        LOADPAIR(B1h[2], B1l[2], mfrag, ((w + 4) * 3 + 2) * 2);
        G0TILE(w, B0h, B0l);
        LOADPAIR(B2h[0], B2l[0], mfrag, ((w + 8) * 3 + 0) * 2);
        LOADPAIR(B2h[1], B2l[1], mfrag, ((w + 8) * 3 + 1) * 2);
        LOADPAIR(B2h[2], B2l[2], mfrag, ((w + 8) * 3 + 2) * 2);
        G0TILE(w + 4, B1h, B1l);
        if (w < 2) {
            LOADPAIR(B3h[0], B3l[0], mfrag, ((w + 12) * 3 + 0) * 2);
            LOADPAIR(B3h[1], B3l[1], mfrag, ((w + 12) * 3 + 1) * 2);
            LOADPAIR(B3h[2], B3l[2], mfrag, ((w + 12) * 3 + 2) * 2);
        }
        G0TILE(w + 8, B2h, B2l);
        if (w < 2) G0TILE(w + 12, B3h, B3l);
        #undef G0TILE
    }
    bar();

    // ---- G1 (MFMA): L^T = gkq(hi/lo) @ xw + bias ; B via u16 gather from XWS ----
    {
        frag_u B[3];
        {
            const int l2 = (w * 16 + (lane & 15)) * 2;
            const int kb = (lane >> 4) << 10;
            #pragma unroll
            for (int j = 0; j < 8; ++j) {
                const int aj = kb + j * 128 + (l2 ^ (j << 4));
                B[0].b[j] = *reinterpret_cast<const __bf16*>(S + XWS + aj);
                B[1].b[j] = *reinterpret_cast<const __bf16*>(S + XWS + 4096 + aj);
                B[2].b[j] = *reinterpret_cast<const __bf16*>(S + XWS + 8192 + aj);
            }
        }
        frag_u Ah[3], Al[3];
        #pragma unroll
        for (int ks = 0; ks < 3; ++ks) {
            const int off = (lane & 15) * 200 + (ks * 32 + (lane >> 4) * 8) * 2;
            Ah[ks].s = *reinterpret_cast<const short8*>(S + GKQH + off);
            Al[ks].s = *reinterpret_cast<const short8*>(S + GKQL + off);
        }
        f32x4 acc = {0.f, 0.f, 0.f, 0.f};
        #pragma unroll
        for (int ks = 0; ks < 3; ++ks) {
            acc = __builtin_amdgcn_mfma_f32_16x16x32_bf16(Ah[ks].b, B[ks].b, acc, 0, 0, 0);
            acc = __builtin_amdgcn_mfma_f32_16x16x32_bf16(Al[ks].b, B[ks].b, acc, 0, 0, 0);
        }
        const int colL = w * 16 + (lane & 15);
        #pragma unroll
        for (int rr = 0; rr < 4; ++rr) {
            const int pr = (lane >> 4) * 4 + rr;
            Lraw[pr * 66 + colL] = acc[rr] + bias16[pr] + (pr < 8 ? scal0 : scal1);
        }
    }
    bar();

    // ---- SM: k-softmax rows over waves; q-softmax + qat hi/lo on wave 3 ----
    if (w < 3) {
        #pragma unroll
        for (int rr = 0; rr < 2; ++rr) {
            const int pp = w + 3 * rr;               // rows 0..5
            const float v = Lraw[pp * 66 + lane];
            float mx = v;
            #pragma unroll
            for (int off = 32; off; off >>= 1) mx = fmaxf(mx, __shfl_xor(mx, off));
            const float e = __expf(v - mx);
            float s = e;
            #pragma unroll
            for (int off = 32; off; off >>= 1) s += __shfl_xor(s, off);
            const float a = e / s;
            const __bf16 hb = (__bf16)a;
            const __bf16 lb = (__bf16)(a - (float)hb);
            const int ks = lane >> 5;
            const int off_b = ((pp + 16 * ((lane >> 3) & 3)) << 4) + ((lane & 7) << 1);
            *reinterpret_cast<__bf16*>(S + RB + (ks << 10) + off_b) = hb;
            *reinterpret_cast<__bf16*>(S + RB + ((2 + ks) << 10) + off_b) = lb;
        }
    } else {
        {
            const int pp = 6;
            const float v = Lraw[pp * 66 + lane];
            float mx = v;
            #pragma unroll
            for (int off = 32; off; off >>= 1) mx = fmaxf(mx, __shfl_xor(mx, off));
            const float e = __expf(v - mx);
            float s = e;
            #pragma unroll
            for (int off = 32; off; off >>= 1) s += __shfl_xor(s, off);
            const float a = e / s;
            const __bf16 hb = (__bf16)a;
            const __bf16 lb = (__bf16)(a - (float)hb);
            const int ks = lane >> 5;
            const int off_b = ((pp + 16 * ((lane >> 3) & 3)) << 4) + ((lane & 7) << 1);
            *reinterpret_cast<__bf16*>(S + RB + (ks << 10) + off_b) = hb;
            *reinterpret_cast<__bf16*>(S + RB + ((2 + ks) << 10) + off_b) = lb;
        }
        float vv[Pp];
        float mx = -1e30f;
        #pragma unroll
        for (int p = 0; p < Pp; ++p) { vv[p] = Lraw[(8 + p) * 66 + lane]; mx = fmaxf(mx, vv[p]); }
        float s = 0.f;
        #pragma unroll
        for (int p = 0; p < Pp; ++p) { vv[p] = __expf(vv[p] - mx); s += vv[p]; }
        const float inv = 1.f / s;
        frag_u qh, ql;
        #pragma unroll
        for (int p = 0; p < 8; ++p) {
            const float a = (p < Pp) ? vv[p] * inv : 0.f;
            const __bf16 hb = (__bf16)a;
            qh.b[p] = hb;
            ql.b[p] = (__bf16)(a - (float)hb);
        }
        *reinterpret_cast<short8*>(S + QATH + lane * 16) = qh.s;
        *reinterpret_cast<short8*>(S + QATL + lane * 16) = ql.s;
    }
    bar();

    // ---- G2 (MFMA) + wvfrag prefetch: xv^T = xw @ attn(hi/lo); write xv hi/lo ----
    frag_u V0h[3], V0l[3], V1h[3], V1l[3];
    {
        LOADPAIR(V0h[0], V0l[0], wvfrag, (w * 3 + 0) * 2);
        LOADPAIR(V0h[1], V0l[1], wvfrag, (w * 3 + 1) * 2);
        LOADPAIR(V0h[2], V0l[2], wvfrag, (w * 3 + 2) * 2);
        if (w < 2) {
            LOADPAIR(V1h[0], V1l[0], wvfrag, ((4 + w) * 3 + 0) * 2);
            LOADPAIR(V1h[1], V1l[1], wvfrag, ((4 + w) * 3 + 1) * 2);
            LOADPAIR(V1h[2], V1l[2], wvfrag, ((4 + w) * 3 + 2) * 2);
        }

        frag_u Bh[2], Bl[2];
        #pragma unroll
        for (int ks = 0; ks < 2; ++ks) {
            Bh[ks].s = *reinterpret_cast<const short8*>(S + RB + (ks << 10) + (lane << 4));
            Bl[ks].s = *reinterpret_cast<const short8*>(S + RB + ((2 + ks) << 10) + (lane << 4));
        }
        const int mt0 = (w < 2) ? w * 2 : (w + 2);
        const int nmt = (w < 2) ? 2 : 1;
        for (int m = 0; m < nmt; ++m) {
            const int mt = mt0 + m;
            f32x4 acc = {0.f, 0.f, 0.f, 0.f};
            #pragma unroll
            for (int ks = 0; ks < 2; ++ks) {
                frag_u A;
                A.s = xws_fragA(S, mt, ks, lane);
                acc = __builtin_amdgcn_mfma_f32_16x16x32_bf16(A.b, Bh[ks].b, acc, 0, 0, 0);
                acc = __builtin_amdgcn_mfma_f32_16x16x32_bf16(A.b, Bl[ks].b, acc, 0, 0, 0);
            }
            const int p = lane & 15;
            if (p < 8) {                              // rows >=8 never read; avoid lo-image clobber
                #pragma unroll
                for (int rr = 0; rr < 4; ++rr) {
                    const int c = mt * 16 + (lane >> 4) * 4 + rr;
                    put_hilo(S, XPH + p * 200 + c * 2, XPL + p * 200 + c * 2, acc[rr]);
                }
            }
        }
    }
    bar();

    // ---- G3 (MFMA): av^T = Wv(hi/lo) @ xv(hi/lo) + bv; write av hi/lo [96][16B] ----
    {
        const bool pok = (lane & 15) < Pp;           // garbage guard (xv row 7 junk cols)
        frag_u Bh[3], Bl[3];
        #pragma unroll
        for (int ks = 0; ks < 3; ++ks) {
            const int off = ((lane & 15) & 7) * 200 + (ks * 32 + (lane >> 4) * 8) * 2;
            Bh[ks].s = pok ? *reinterpret_cast<const short8*>(S + XPH + off) : zero8;
            Bl[ks].s = pok ? *reinterpret_cast<const short8*>(S + XPL + off) : zero8;
        }
        #define G3TILE(MT, VH, VL) do {                                               \
            f32x4 acc = {0.f, 0.f, 0.f, 0.f};                                         \
            acc = __builtin_amdgcn_mfma_f32_16x16x32_bf16(VH[0].b, Bh[0].b, acc, 0,0,0); \
            acc = __builtin_amdgcn_mfma_f32_16x16x32_bf16(VH[0].b, Bl[0].b, acc, 0,0,0); \
            acc = __builtin_amdgcn_mfma_f32_16x16x32_bf16(VL[0].b, Bh[0].b, acc, 0,0,0); \
            acc = __builtin_amdgcn_mfma_f32_16x16x32_bf16(VH[1].b, Bh[1].b, acc, 0,0,0); \
            acc = __builtin_amdgcn_mfma_f32_16x16x32_bf16(VH[1].b, Bl[1].b, acc, 0,0,0); \
            acc = __builtin_amdgcn_mfma_f32_16x16x32_bf16(VL[1].b, Bh[1].b, acc, 0,0,0); \
            acc = __builtin_amdgcn_mfma_f32_16x16x32_bf16(VH[2].b, Bh[2].b, acc, 0,0,0); \
            acc = __builtin_amdgcn_mfma_f32_16x16x32_bf16(VH[2].b, Bl[2].b, acc, 0,0,0); \
            acc = __builtin_amdgcn_mfma_f32_16x16x32_bf16(VL[2].b, Bh[2].b, acc, 0,0,0); \
            if ((lane & 15) < 8) {                                                    \
                _Pragma("unroll")                                                     \
                for (int rr = 0; rr < 4; ++rr) {                                      \
                    const int o_ = (MT) * 16 + (lane >> 4) * 4 + rr;                  \
                    const float v_ = acc[rr] + bv[o_];                                \
                    put_hilo(S, AVH + o_ * 16 + (lane & 15) * 2,                      \
                             AVL + o_ * 16 + (lane & 15) * 2, v_);                    \
                }                                                                     \
            }                                                                         \
        } while (0)
        G3TILE(w, V0h, V0l);
        if (w < 2) G3TILE(4 + w, V1h, V1l);
        #undef G3TILE
    }
    bar();

    // ---- P7 (MFMA): out^T[96o][64l] = av_ext @ qat^T (K=32; k>=8 zero in-register) ----
    {
        const int kblk = lane >> 4, nlow = lane & 15;
        const int l = w * 16 + nlow;
        frag_u Bh, Bl;
        if (kblk == 0) {
            Bh.s = *reinterpret_cast<const short8*>(S + QATH + l * 16);
            Bl.s = *reinterpret_cast<const short8*>(S + QATL + l * 16);
        } else { Bh.s = zero8; Bl.s = zero8; }
        const int obase = b * C_ * HWp + (h0 + (l >> 3)) * Wimg + w0 + (l & 7);
        #pragma unroll
        for (int mt = 0; mt < 6; ++mt) {
            frag_u Ah, Al;
            if (kblk == 0) {
                Ah.s = *reinterpret_cast<const short8*>(S + AVH + (mt * 16 + nlow) * 16);
                Al.s = *reinterpret_cast<const short8*>(S + AVL + (mt * 16 + nlow) * 16);
            } else { Ah.s = zero8; Al.s = zero8; }
            f32x4 acc = {0.f, 0.f, 0.f, 0.f};
            acc = __builtin_amdgcn_mfma_f32_16x16x32_bf16(Ah.b, Bh.b, acc, 0, 0, 0);
            acc = __builtin_amdgcn_mfma_f32_16x16x32_bf16(Ah.b, Bl.b, acc, 0, 0, 0);
            acc = __builtin_amdgcn_mfma_f32_16x16x32_bf16(Al.b, Bh.b, acc, 0, 0, 0);
            #pragma unroll
            for (int rr = 0; rr < 4; ++rr) {
                const int o = mt * 16 + kblk * 4 + rr;
                out[obase + o * HWp] = acc[rr];
            }
        }
    }
}

// ---------------- launch ----------------

extern "C" void kernel_launch(void* const* d_in, const int* in_sizes, int n_in,
                              void* d_out, int out_size, void* d_ws, size_t ws_size,
                              hipStream_t stream)
{
    const float* x  = (const float*)d_in[0];
    const float* Wv = (const float*)d_in[1];
    const float* bv = (const float*)d_in[2];
    const float* Wq = (const float*)d_in[3];
    const float* bq = (const float*)d_in[4];
    const float* Wk = (const float*)d_in[5];
    const float* bk = (const float*)d_in[6];
    float* out = (float*)d_out;

    float* ws = (float*)d_ws;
    float* Mk   = ws;                 // 9216
    float* Mq   = ws + 9216;          // 9216
    float* uk   = ws + 18432;
    float* uq   = ws + 18528;
    float* bk2  = ws + 18624;
    float* bq2  = ws + 18720;
    float* scal = ws + 18816;
    unsigned char* wsb = (unsigned char*)d_ws;

    hipLaunchKernelGGL(precompute_mats, dim3(C_), dim3(C_), 0, stream,
                       Wq, Wk, Mk, Mq);
    hipLaunchKernelGGL(precompute_vecs, dim3(1), dim3(C_), 0, stream,
                       Wq, Wk, bq, bk, uk, uq, bk2, bq2, scal);
    hipLaunchKernelGGL(precompute_frags, dim3(120), dim3(64), 0, stream,
                       ws, Wv, wsb);
    hipLaunchKernelGGL(camixer_main, dim3(8 * NWIN * NWIN), dim3(256), 0, stream,
                       x, bv, bk2, bq2, scal,
                       wsb + WS_FRAG_BYTE, wsb + WS_WV_BYTE, out);
}